// Round 3
// baseline (118.492 us; speedup 1.0000x reference)
//
#include <hip/hip_runtime.h>
#include <math.h>

#define N_NODES 8192
#define WPR 256               // words per bitmask row = N/32
#define LR_C 0.01f
#define EPS_C 1e-6f
#define NJ 32                 // j-chunks in repulsion

// ---------------- K0: clear A,B (16MiB) + deg (32KB) + copy x1 ----------------
// grid = 4096 x 256: each thread one uint4 (16B) -> exactly 16 MiB.
__global__ __launch_bounds__(256) void init_clear(const float4* __restrict__ pos4,
                                                  float4* __restrict__ x1_4,
                                                  uint4* __restrict__ adj,
                                                  uint4* __restrict__ deg4) {
    int gid = blockIdx.x * blockDim.x + threadIdx.x;
    adj[gid] = make_uint4(0u, 0u, 0u, 0u);
    if (gid < 6144) x1_4[gid] = pos4[gid];           // 8192*3 floats
    if (gid < 2048) deg4[gid] = make_uint4(0u, 0u, 0u, 0u);  // 8192 ints
}

// ---------------- K1: fused constraint-scatter + adjacency(+degree) ----------------
// blocks [0,nbK): scatter over K pairs; blocks [nbK, nbK+nbE): edges
__global__ __launch_bounds__(256) void scatter_adj(
        const float* __restrict__ x0, const int* __restrict__ dist_idx,
        const float* __restrict__ dist_target, const int* __restrict__ edge_index,
        float* __restrict__ x1, unsigned int* __restrict__ A,
        unsigned int* __restrict__ B, int* __restrict__ deg,
        int K, int E, int nbK) {
    int blk = blockIdx.x;
    if (blk < nbK) {
        int k = blk * 256 + threadIdx.x;
        if (k >= K) return;
        int i = dist_idx[2 * k], j = dist_idx[2 * k + 1];
        float ax = x0[3 * i], ay = x0[3 * i + 1], az = x0[3 * i + 2];
        float bx = x0[3 * j], by = x0[3 * j + 1], bz = x0[3 * j + 2];
        float vx = ax - bx, vy = ay - by, vz = az - bz;
        float dist = sqrtf(vx * vx + vy * vy + vz * vz + 1e-12f);
        bool valid = (dist > EPS_C) && (i != j);
        float coef = valid ? (LR_C * 0.5f) * (dist - dist_target[k]) / dist : 0.0f;
        if (coef != 0.0f) {
            float cx = coef * vx, cy = coef * vy, cz = coef * vz;
            atomicAdd(&x1[3 * i],     -cx);
            atomicAdd(&x1[3 * i + 1], -cy);
            atomicAdd(&x1[3 * i + 2], -cz);
            atomicAdd(&x1[3 * j],      cx);
            atomicAdd(&x1[3 * j + 1],  cy);
            atomicAdd(&x1[3 * j + 2],  cz);
        }
    } else {
        int k = (blk - nbK) * 256 + threadIdx.x;
        if (k >= E) return;
        int a = edge_index[k];
        int b = edge_index[E + k];
        a = min(max(a, 0), N_NODES - 1);
        b = min(max(b, 0), N_NODES - 1);
        unsigned int bitb = 1u << (b & 31);
        unsigned int bita = 1u << (a & 31);
        unsigned int old = atomicOr(&A[a * WPR + (b >> 5)], bitb);
        if (!(old & bitb)) atomicAdd(&deg[a], 1);
        old = atomicOr(&B[b * WPR + (a >> 5)], bita);
        if (!(old & bita)) atomicAdd(&deg[b], 1);
    }
}

// ---------------- K2: pairwise repulsion partials ----------------
// grid = (32 i-chunks, 32 j-chunks), block = 256
__global__ __launch_bounds__(256) void repulsion_partial(
        const float* __restrict__ x1, const float* __restrict__ min_dist,
        float4* __restrict__ partials) {
    __shared__ float4 pj[256];
    int t = threadIdx.x;
    int jbase = blockIdx.y * 256;
    int i = blockIdx.x * 256 + t;
    {
        int j = jbase + t;
        float a = x1[3 * j], b = x1[3 * j + 1], c = x1[3 * j + 2];
        pj[t] = make_float4(a, b, c, a * a + b * b + c * c);
    }
    __syncthreads();
    float xi = x1[3 * i], yi = x1[3 * i + 1], zi = x1[3 * i + 2];
    float sqi = xi * xi + yi * yi + zi * zi;
    float md = min_dist[0];
    const float c0 = 0.5f * LR_C;          // 0.005
    float c1 = c0 * md;
    float S = 0.f, axc = 0.f, ayc = 0.f, azc = 0.f;
    if (blockIdx.x == blockIdx.y) {
        // diagonal tile: must exclude self-pair explicitly (cancellation can
        // leave tiny positive d2 for i==j, which the reference excludes exactly)
        int di = t;
        #pragma unroll 4
        for (int jj = 0; jj < 256; ++jj) {
            float4 p = pj[jj];
            float dot = fmaf(xi, p.x, fmaf(yi, p.y, zi * p.z));
            float d2 = fmaf(-2.0f, dot, sqi + p.w);
            float r = __builtin_amdgcn_rsqf(fmaxf(d2, 1e-12f));
            float w = fmaxf(fmaf(c1, r, -c0), 0.0f);      // >0 iff d < md
            w = (d2 > 1e-12f && jj != di) ? w : 0.0f;     // exclude overlap + self
            S += w;
            axc = fmaf(w, p.x, axc);
            ayc = fmaf(w, p.y, ayc);
            azc = fmaf(w, p.z, azc);
        }
    } else {
        #pragma unroll 4
        for (int jj = 0; jj < 256; ++jj) {
            float4 p = pj[jj];
            float dot = fmaf(xi, p.x, fmaf(yi, p.y, zi * p.z));
            float d2 = fmaf(-2.0f, dot, sqi + p.w);
            float r = __builtin_amdgcn_rsqf(fmaxf(d2, 1e-12f));
            float w = fmaxf(fmaf(c1, r, -c0), 0.0f);
            w = (d2 > 1e-12f) ? w : 0.0f;                 // exclude exact overlap
            S += w;
            axc = fmaf(w, p.x, axc);
            ayc = fmaf(w, p.y, ayc);
            azc = fmaf(w, p.z, azc);
        }
    }
    partials[blockIdx.y * N_NODES + i] = make_float4(axc, ayc, azc, S);
}

// ---------------- K3: finalize x2 + dinv + z (thread per row) ----------------
__global__ __launch_bounds__(256) void finalize(
        const float* __restrict__ x1, const float4* __restrict__ partials,
        const int* __restrict__ deg,
        float* __restrict__ x2, float* __restrict__ out_x,
        float* __restrict__ dinv, float4* __restrict__ z4) {
    int i = blockIdx.x * blockDim.x + threadIdx.x;
    if (i >= N_NODES) return;
    float S = 0.f, axc = 0.f, ayc = 0.f, azc = 0.f;
    #pragma unroll
    for (int c = 0; c < NJ; ++c) {
        float4 p = partials[c * N_NODES + i];
        axc += p.x; ayc += p.y; azc += p.z; S += p.w;
    }
    float xi = x1[3 * i], yi = x1[3 * i + 1], zi = x1[3 * i + 2];
    float ox = xi + xi * S - axc;
    float oy = yi + yi * S - ayc;
    float oz = zi + zi * S - azc;
    x2[3 * i] = ox; x2[3 * i + 1] = oy; x2[3 * i + 2] = oz;
    out_x[3 * i] = ox; out_x[3 * i + 1] = oy; out_x[3 * i + 2] = oz;
    int d = deg[i];
    float dv = (d == 0) ? 0.0f : 1.0f / sqrtf((float)d + EPS_C);
    dinv[i] = dv;
    z4[i] = make_float4(dv * ox, dv * oy, dv * oz, dv);
}

// ---------------- K4: Laplacian gather + curvature (wave per row) ----------------
__global__ __launch_bounds__(256) void lap_kernel(
        const unsigned int* __restrict__ A, const unsigned int* __restrict__ B,
        const float* __restrict__ x2, const float* __restrict__ dinv,
        const float4* __restrict__ z4, float* __restrict__ out_curv) {
    int row = (blockIdx.x * blockDim.x + threadIdx.x) >> 6;
    int lane = threadIdx.x & 63;
    if (row >= N_NODES) return;
    float axc = 0.f, ayc = 0.f, azc = 0.f;
    #pragma unroll
    for (int q = 0; q < 4; ++q) {
        int wi = q * 64 + lane;
        unsigned int w = A[(size_t)row * WPR + wi];
        while (w) {
            int b = __ffs(w) - 1; w &= w - 1;
            float4 z = z4[wi * 32 + b];
            axc += z.x; ayc += z.y; azc += z.z;
        }
        w = B[(size_t)row * WPR + wi];
        while (w) {
            int b = __ffs(w) - 1; w &= w - 1;
            float4 z = z4[wi * 32 + b];
            axc += z.x; ayc += z.y; azc += z.z;
        }
    }
    for (int off = 32; off; off >>= 1) {
        axc += __shfl_down(axc, off);
        ayc += __shfl_down(ayc, off);
        azc += __shfl_down(azc, off);
    }
    if (lane == 0) {
        float dv = dinv[row];
        float lx = x2[3 * row]     - dv * axc;
        float ly = x2[3 * row + 1] - dv * ayc;
        float lz = x2[3 * row + 2] - dv * azc;
        out_curv[row] = sqrtf(lx * lx + ly * ly + lz * lz + 1e-12f);
    }
}

extern "C" void kernel_launch(void* const* d_in, const int* in_sizes, int n_in,
                              void* d_out, int out_size, void* d_ws, size_t ws_size,
                              hipStream_t stream) {
    const float* positions   = (const float*)d_in[0];
    const int*   edge_index  = (const int*)d_in[1];
    const int*   dist_idx    = (const int*)d_in[2];
    const float* dist_target = (const float*)d_in[3];
    const float* min_dist    = (const float*)d_in[4];
    float* out = (float*)d_out;

    const int E = in_sizes[1] / 2;   // 262144
    const int K = in_sizes[2] / 2;   // 65536

    // workspace layout (16B aligned)
    char* ws = (char*)d_ws;
    const size_t X1_OFF   = 0;
    const size_t X2_OFF   = X1_OFF + (size_t)N_NODES * 3 * 4;          //  96 KiB
    const size_t Z4_OFF   = X2_OFF + (size_t)N_NODES * 3 * 4;          //  96 KiB
    const size_t DINV_OFF = Z4_OFF + (size_t)N_NODES * 16;             // 128 KiB
    const size_t DEG_OFF  = DINV_OFF + (size_t)N_NODES * 4;            //  32 KiB
    const size_t PART_OFF = DEG_OFF + (size_t)N_NODES * 4;             //  32 KiB
    const size_t ADJ_OFF  = PART_OFF + (size_t)NJ * N_NODES * 16;      //   4 MiB
    const size_t ADJ_BYTES = (size_t)N_NODES * WPR * 4;                //   8 MiB each

    float* x1         = (float*)(ws + X1_OFF);
    float* x2         = (float*)(ws + X2_OFF);
    float4* z4        = (float4*)(ws + Z4_OFF);
    float* dinv       = (float*)(ws + DINV_OFF);
    int*   deg        = (int*)(ws + DEG_OFF);
    float4* partials  = (float4*)(ws + PART_OFF);
    unsigned int* A   = (unsigned int*)(ws + ADJ_OFF);
    unsigned int* B   = (unsigned int*)(ws + ADJ_OFF + ADJ_BYTES);

    init_clear<<<4096, 256, 0, stream>>>((const float4*)positions,
                                         (float4*)x1, (uint4*)A, (uint4*)deg);

    int nbK = (K + 255) / 256;           // 256
    int nbE = (E + 255) / 256;           // 1024
    scatter_adj<<<nbK + nbE, 256, 0, stream>>>(
        positions, dist_idx, dist_target, edge_index, x1, A, B, deg, K, E, nbK);

    dim3 grid_rep(N_NODES / 256, NJ);
    repulsion_partial<<<grid_rep, 256, 0, stream>>>(x1, min_dist, partials);

    finalize<<<N_NODES / 256, 256, 0, stream>>>(x1, partials, deg,
                                                x2, out, dinv, z4);

    lap_kernel<<<N_NODES / 4, 256, 0, stream>>>(A, B, x2, dinv, z4,
                                                out + 3 * N_NODES);
}